// Round 6
// baseline (128.156 us; speedup 1.0000x reference)
//
#include <hip/hip_runtime.h>
#include <hip/hip_bf16.h>

typedef __bf16 bf16_t;
typedef __bf16 bf16x4 __attribute__((ext_vector_type(4)));
typedef __bf16 bf16x8 __attribute__((ext_vector_type(8)));
typedef float f32x4 __attribute__((ext_vector_type(4)));

#define M_TOT 8192
#define N_TOT 512
#define K_TOT 2048
#define E_TOT 512
#define NT    32          // K-tiles of 64

__device__ __forceinline__ bf16x8 zero8() {
    bf16x8 v;
#pragma unroll
    for (int i = 0; i < 8; ++i) v[i] = (bf16_t)0.0f;
    return v;
}

// ---------------------------------------------------------------------------
// prep4:
//  blocks [0,256):   LDS-tiled transpose W2[k][n] -> W2t[n][k] bf16
//  blocks [256,288): zb[m][0..8)=cos(theta[q])*cos(x[m,q]) (RX collapse:
//                    |a2|^2-|b2|^2 = cos(theta)*cos(x)); zb[m][8]=1; rest 0
//  blocks [288,296): W1p: PERMUTED W1 rows + bias, 16 k-slots per row.
//    Row d=(c*2+p)*16+rr holds original column f = c*32+(rr>>2)*8+p*4+(rr&3)
//    so that h-MFMA p of chunk c lands its C-output exactly in the main
//    MFMA's A-fragment layout (lane gets f = c*32 + lq*8 + p*4 + r).
// ---------------------------------------------------------------------------
__global__ __launch_bounds__(256)
void prep4_kernel(const float* __restrict__ x,
                  const float* __restrict__ theta,
                  const float* __restrict__ W1,
                  const float* __restrict__ b1,
                  const float* __restrict__ W2,
                  bf16_t* __restrict__ W2t,
                  bf16_t* __restrict__ zb,
                  bf16_t* __restrict__ W1p)
{
    const int b = blockIdx.x;
    if (b < 256) {
        __shared__ bf16_t T[64][66];
        const int k0 = (b >> 3) * 64;
        const int n0 = (b & 7) * 64;
        const int kl = threadIdx.x >> 4;
        const int n4 = threadIdx.x & 15;
#pragma unroll
        for (int i = 0; i < 4; ++i) {
            int k = kl + i * 16;
            float4 v = *(const float4*)(W2 + (size_t)(k0 + k) * N_TOT + n0 + n4 * 4);
            T[n4 * 4 + 0][k] = (bf16_t)v.x;
            T[n4 * 4 + 1][k] = (bf16_t)v.y;
            T[n4 * 4 + 2][k] = (bf16_t)v.z;
            T[n4 * 4 + 3][k] = (bf16_t)v.w;
        }
        __syncthreads();
        const int nl = threadIdx.x >> 4;
        const int k4 = threadIdx.x & 15;
#pragma unroll
        for (int i = 0; i < 4; ++i) {
            int n = nl + i * 16;
            bf16x4 v;
            v[0] = T[n][k4 * 4 + 0];
            v[1] = T[n][k4 * 4 + 1];
            v[2] = T[n][k4 * 4 + 2];
            v[3] = T[n][k4 * 4 + 3];
            *(bf16x4*)(W2t + (size_t)(n0 + n) * K_TOT + k0 + k4 * 4) = v;
        }
    } else if (b < 288) {
        const int m = (b - 256) * 256 + threadIdx.x;
        float4 x0 = *(const float4*)(x + (size_t)m * E_TOT);
        float4 x1 = *(const float4*)(x + (size_t)m * E_TOT + 4);
        float xs[8] = {x0.x, x0.y, x0.z, x0.w, x1.x, x1.y, x1.z, x1.w};
        bf16x8 lo;
#pragma unroll
        for (int q = 0; q < 8; ++q)
            lo[q] = (bf16_t)(__builtin_cosf(theta[q]) * __builtin_cosf(xs[q]));
        bf16x8 hi = zero8();
        hi[0] = (bf16_t)1.0f;                  // bias lane at k=8
        *(bf16x8*)(zb + (size_t)m * 16)     = lo;
        *(bf16x8*)(zb + (size_t)m * 16 + 8) = hi;
    } else {
        const int d  = (b - 288) * 256 + threadIdx.x;    // 0..2047
        const int c  = d >> 5;
        const int dd = d & 31;
        const int p  = dd >> 4;
        const int rr = dd & 15;
        const int f  = c * 32 + ((rr >> 2) << 3) + (p << 2) + (rr & 3);
        bf16x8 lo;
#pragma unroll
        for (int q = 0; q < 8; ++q)
            lo[q] = (bf16_t)W1[(size_t)q * K_TOT + f];
        bf16x8 hi = zero8();
        hi[0] = (bf16_t)b1[f];                 // bias at k=8
        *(bf16x8*)(W1p + (size_t)d * 16)     = lo;
        *(bf16x8*)(W1p + (size_t)d * 16 + 8) = hi;
    }
}

// ---------------------------------------------------------------------------
// helpers (512-thread block)
// ---------------------------------------------------------------------------
// B tile: 128n x 64k bf16 = 16KB. Thread t stages 2x16B through VGPRs.
// LDS slot `seg` of row n holds global k-seg g = seg ^ (n&7) (xor swizzle).
__device__ __forceinline__ void load_B(const bf16_t* __restrict__ W2t, int n_base,
                                       int k0, int t, uint4 gv[2]) {
#pragma unroll
    for (int j = 0; j < 2; ++j) {
        int s = t + j * 512;
        int n = s >> 3;
        int g = (s & 7) ^ (n & 7);
        gv[j] = *(const uint4*)(W2t + (size_t)(n_base + n) * K_TOT + k0 + g * 8);
    }
}
__device__ __forceinline__ void write_B(bf16_t* Bb, int t, const uint4 gv[2]) {
#pragma unroll
    for (int j = 0; j < 2; ++j) {
        int s = t + j * 512;
        *(uint4*)(Bb + (s >> 3) * 64 + (s & 7) * 8) = gv[j];
    }
}

// W1p frags for one K-tile (2 chunks x 2 perm-halves); only lanes lq<2 real.
__device__ __forceinline__ void load_wf(const bf16_t* __restrict__ W1p, int k0,
                                        int l15, int lq, bf16x8 wf[4]) {
#pragma unroll
    for (int i = 0; i < 4; ++i) wf[i] = zero8();
    if (lq < 2) {
        const int base = (k0 >> 5) * 2;      // row-group of chunk c=0
#pragma unroll
        for (int i = 0; i < 4; ++i)          // i = c*2+p
            wf[i] = *(const bf16x8*)(W1p + (size_t)((base + i) * 16 + l15) * 16 + lq * 8);
    }
}

// one K-tile: B frags from LDS, h in registers (layout-matched MFMA), mains.
__device__ __forceinline__ void compute_tile(const bf16_t* Bb, const bf16x8 wf[4],
                                             const bf16x8 zfrag[2],
                                             int wn, int l15, int lq,
                                             f32x4 acc[2][4]) {
    // start LDS reads early; h-MFMAs below have no LDS dependency
    bf16x8 bfr[2][4];
#pragma unroll
    for (int c = 0; c < 2; ++c)
#pragma unroll
        for (int nt = 0; nt < 4; ++nt) {
            int r = wn * 64 + nt * 16 + l15;
            int s = (c * 4 + lq) ^ (r & 7);
            bfr[c][nt] = *(const bf16x8*)(Bb + r * 64 + s * 8);
        }

    // h tile: af[mt][c] = relu(z@W1+b1) already in main-A fragment layout
    bf16x8 af[2][2];
#pragma unroll
    for (int mt = 0; mt < 2; ++mt)
#pragma unroll
        for (int c = 0; c < 2; ++c) {
            f32x4 h0 = (f32x4){0.f, 0.f, 0.f, 0.f};
            f32x4 h1 = (f32x4){0.f, 0.f, 0.f, 0.f};
            h0 = __builtin_amdgcn_mfma_f32_16x16x32_bf16(wf[c * 2 + 0], zfrag[mt], h0, 0, 0, 0);
            h1 = __builtin_amdgcn_mfma_f32_16x16x32_bf16(wf[c * 2 + 1], zfrag[mt], h1, 0, 0, 0);
            bf16x8 a;
#pragma unroll
            for (int r = 0; r < 4; ++r) {
                a[r]     = (bf16_t)fmaxf(h0[r], 0.f);
                a[r + 4] = (bf16_t)fmaxf(h1[r], 0.f);
            }
            af[mt][c] = a;
        }

    // main MFMAs
#pragma unroll
    for (int c = 0; c < 2; ++c)
#pragma unroll
        for (int mt = 0; mt < 2; ++mt)
#pragma unroll
            for (int nt = 0; nt < 4; ++nt)
                acc[mt][nt] = __builtin_amdgcn_mfma_f32_16x16x32_bf16(
                    af[mt][c], bfr[c][nt], acc[mt][nt], 0, 0, 0);
}

// ---------------------------------------------------------------------------
// Fused GEMM: out = relu(z@W1+b1) @ W2 + b2
// 128x128 tile, 512 thr = 8 waves (4m x 2n), wave 32m x 64n.
// B-only dbuf LDS (32KB) staged via VGPRs; h entirely in registers via
// layout-matched h-MFMA (permuted W1p). ONE barrier per K-tile.
// ---------------------------------------------------------------------------
__global__ __launch_bounds__(512, 2)
void ffq_gemm_kernel(const bf16_t* __restrict__ zb,    // [8192][16]
                     const bf16_t* __restrict__ W1p,   // [2048][16] permuted
                     const bf16_t* __restrict__ W2t,   // [512][2048]
                     const float* __restrict__ b2,
                     float* __restrict__ out)          // [8192][512]
{
    __shared__ bf16_t Blds[2][128 * 64];   // 2 x 16KB, slot = kseg^(n&7)

    const int t = threadIdx.x;
    const int w = t >> 6, l = t & 63;
    const int m_base = blockIdx.y * 128;
    const int n_base = blockIdx.x * 128;
    const int wm = w >> 1, wn = w & 1;      // 4m x 2n waves
    const int l15 = l & 15, lq = l >> 4;

    // persistent z^T B-frags for this wave's two 16-row m-tiles
    bf16x8 zfrag[2];
#pragma unroll
    for (int mt = 0; mt < 2; ++mt) {
        zfrag[mt] = zero8();
        if (lq < 2)
            zfrag[mt] = *(const bf16x8*)(zb + (size_t)(m_base + wm * 32 + mt * 16 + l15) * 16 + lq * 8);
    }

    f32x4 acc[2][4];
#pragma unroll
    for (int mt = 0; mt < 2; ++mt)
#pragma unroll
        for (int nt = 0; nt < 4; ++nt)
            acc[mt][nt] = (f32x4){0.f, 0.f, 0.f, 0.f};

    uint4 gv[2];
    bf16x8 wfA[4], wfB[4];

    // prologue: stage tile 0 into buf0; wf for tile 0
    load_B(W2t, n_base, 0, t, gv);
    load_wf(W1p, 0, l15, lq, wfA);
    write_B(Blds[0], t, gv);

    for (int it = 0; it < NT; it += 2) {
        // ---- tile it (buf0, wfA); prefetch it+1 ----
        __syncthreads();                                // publish buf0
        load_B(W2t, n_base, (it + 1) * 64, t, gv);
        load_wf(W1p, (it + 1) * 64, l15, lq, wfB);
        compute_tile(Blds[0], wfA, zfrag, wn, l15, lq, acc);
        write_B(Blds[1], t, gv);                        // precise vmcnt wait

        // ---- tile it+1 (buf1, wfB); prefetch it+2 ----
        __syncthreads();                                // publish buf1
        const bool more = (it + 2 < NT);
        if (more) {
            load_B(W2t, n_base, (it + 2) * 64, t, gv);
            load_wf(W1p, (it + 2) * 64, l15, lq, wfA);
        }
        compute_tile(Blds[1], wfB, zfrag, wn, l15, lq, acc);
        if (more) write_B(Blds[0], t, gv);
    }

    // ---- epilogue: C/D layout col=lane&15, row=(lane>>4)*4+r ----
#pragma unroll
    for (int nt = 0; nt < 4; ++nt) {
        int col = n_base + wn * 64 + nt * 16 + l15;
        float bias = b2[col];
#pragma unroll
        for (int mt = 0; mt < 2; ++mt) {
#pragma unroll
            for (int r = 0; r < 4; ++r) {
                int row = m_base + wm * 32 + mt * 16 + lq * 4 + r;
                out[(size_t)row * N_TOT + col] = acc[mt][nt][r] + bias;
            }
        }
    }
}

extern "C" void kernel_launch(void* const* d_in, const int* in_sizes, int n_in,
                              void* d_out, int out_size, void* d_ws, size_t ws_size,
                              hipStream_t stream) {
    const float* x     = (const float*)d_in[0];
    const float* theta = (const float*)d_in[1];
    const float* W1    = (const float*)d_in[2];
    const float* b1    = (const float*)d_in[3];
    const float* W2    = (const float*)d_in[4];
    const float* b2    = (const float*)d_in[5];
    float* out = (float*)d_out;

    // ws: [0,2MB) W2t ; [2MB,2.25MB) zb[8192][16] ; then W1p[2048][16]
    const size_t W2T_BYTES = (size_t)N_TOT * K_TOT * sizeof(bf16_t);  // 2 MB
    const size_t ZB_BYTES  = (size_t)M_TOT * 16 * sizeof(bf16_t);     // 256 KB

    bf16_t* W2t = (bf16_t*)d_ws;
    bf16_t* zb  = (bf16_t*)((char*)d_ws + W2T_BYTES);
    bf16_t* W1p = (bf16_t*)((char*)d_ws + W2T_BYTES + ZB_BYTES);

    prep4_kernel<<<296, 256, 0, stream>>>(x, theta, W1, b1, W2, W2t, zb, W1p);

    dim3 grid(N_TOT / 128, M_TOT / 128);   // (4, 64) = 256 blocks
    ffq_gemm_kernel<<<grid, 512, 0, stream>>>(zb, W1p, W2t, b2, out);
}

// Round 7
// 107.613 us; speedup vs baseline: 1.1909x; 1.1909x over previous
//
#include <hip/hip_runtime.h>
#include <hip/hip_bf16.h>

typedef __bf16 bf16_t;
typedef __bf16 bf16x4 __attribute__((ext_vector_type(4)));
typedef __bf16 bf16x8 __attribute__((ext_vector_type(8)));
typedef float f32x4 __attribute__((ext_vector_type(4)));

#define M_TOT 8192
#define N_TOT 512
#define K_TOT 2048
#define E_TOT 512
#define NSEG  16          // K segments of 128

__device__ __forceinline__ bf16x8 zero8() {
    bf16x8 v;
#pragma unroll
    for (int i = 0; i < 8; ++i) v[i] = (bf16_t)0.0f;
    return v;
}

// ---------------------------------------------------------------------------
// prep4 (unchanged from r6; correctness-proven):
//  blocks [0,256):   LDS-tiled transpose W2[k][n] -> W2t[n][k] bf16
//  blocks [256,288): zb[m][0..8)=cos(theta[q])*cos(x[m,q]) (RX collapse:
//                    |a2|^2-|b2|^2 = cos(theta)*cos(x)); zb[m][8]=1; rest 0
//  blocks [288,296): W1p: permuted W1 rows + bias so h-MFMA C-output lands
//    exactly in main-MFMA A-fragment layout.
//    Row d=(c*2+p)*16+rr holds f = c*32+(rr>>2)*8+p*4+(rr&3).
// ---------------------------------------------------------------------------
__global__ __launch_bounds__(256)
void prep4_kernel(const float* __restrict__ x,
                  const float* __restrict__ theta,
                  const float* __restrict__ W1,
                  const float* __restrict__ b1,
                  const float* __restrict__ W2,
                  bf16_t* __restrict__ W2t,
                  bf16_t* __restrict__ zb,
                  bf16_t* __restrict__ W1p)
{
    const int b = blockIdx.x;
    if (b < 256) {
        __shared__ bf16_t T[64][66];
        const int k0 = (b >> 3) * 64;
        const int n0 = (b & 7) * 64;
        const int kl = threadIdx.x >> 4;
        const int n4 = threadIdx.x & 15;
#pragma unroll
        for (int i = 0; i < 4; ++i) {
            int k = kl + i * 16;
            float4 v = *(const float4*)(W2 + (size_t)(k0 + k) * N_TOT + n0 + n4 * 4);
            T[n4 * 4 + 0][k] = (bf16_t)v.x;
            T[n4 * 4 + 1][k] = (bf16_t)v.y;
            T[n4 * 4 + 2][k] = (bf16_t)v.z;
            T[n4 * 4 + 3][k] = (bf16_t)v.w;
        }
        __syncthreads();
        const int nl = threadIdx.x >> 4;
        const int k4 = threadIdx.x & 15;
#pragma unroll
        for (int i = 0; i < 4; ++i) {
            int n = nl + i * 16;
            bf16x4 v;
            v[0] = T[n][k4 * 4 + 0];
            v[1] = T[n][k4 * 4 + 1];
            v[2] = T[n][k4 * 4 + 2];
            v[3] = T[n][k4 * 4 + 3];
            *(bf16x4*)(W2t + (size_t)(n0 + n) * K_TOT + k0 + k4 * 4) = v;
        }
    } else if (b < 288) {
        const int m = (b - 256) * 256 + threadIdx.x;
        float4 x0 = *(const float4*)(x + (size_t)m * E_TOT);
        float4 x1 = *(const float4*)(x + (size_t)m * E_TOT + 4);
        float xs[8] = {x0.x, x0.y, x0.z, x0.w, x1.x, x1.y, x1.z, x1.w};
        bf16x8 lo;
#pragma unroll
        for (int q = 0; q < 8; ++q)
            lo[q] = (bf16_t)(__builtin_cosf(theta[q]) * __builtin_cosf(xs[q]));
        bf16x8 hi = zero8();
        hi[0] = (bf16_t)1.0f;                  // bias lane at k=8
        *(bf16x8*)(zb + (size_t)m * 16)     = lo;
        *(bf16x8*)(zb + (size_t)m * 16 + 8) = hi;
    } else {
        const int d  = (b - 288) * 256 + threadIdx.x;    // 0..2047
        const int c  = d >> 5;
        const int dd = d & 31;
        const int p  = dd >> 4;
        const int rr = dd & 15;
        const int f  = c * 32 + ((rr >> 2) << 3) + (p << 2) + (rr & 3);
        bf16x8 lo;
#pragma unroll
        for (int q = 0; q < 8; ++q)
            lo[q] = (bf16_t)W1[(size_t)q * K_TOT + f];
        bf16x8 hi = zero8();
        hi[0] = (bf16_t)b1[f];                 // bias at k=8
        *(bf16x8*)(W1p + (size_t)d * 16)     = lo;
        *(bf16x8*)(W1p + (size_t)d * 16 + 8) = hi;
    }
}

// ---------------------------------------------------------------------------
// helpers (256-thread block, block tile 128m x 64n, segment BK=128)
// ---------------------------------------------------------------------------
// B segment: 64n x 128k bf16 = 16KB, stored as two 64x64 k-tiles.
// Within a k-tile, LDS slot `seg` of row n holds global k-seg g = seg^(n&7).
__device__ __forceinline__ void load_B(const bf16_t* __restrict__ W2t, int n_base,
                                       int k0, int t, uint4 gv[4]) {
#pragma unroll
    for (int j = 0; j < 4; ++j) {
        int s    = t + j * 256;        // 0..1023
        int tile = s >> 9;             // 0..1 (which 64-k tile)
        int n    = (s >> 3) & 63;
        int g    = (s & 7) ^ (n & 7);
        gv[j] = *(const uint4*)(W2t + (size_t)(n_base + n) * K_TOT
                                + k0 + tile * 64 + g * 8);
    }
}
__device__ __forceinline__ void write_B(bf16_t* Bb, int t, const uint4 gv[4]) {
#pragma unroll
    for (int j = 0; j < 4; ++j) {
        int s    = t + j * 256;
        int tile = s >> 9;
        int n    = (s >> 3) & 63;
        int seg  = s & 7;
        *(uint4*)(Bb + tile * 4096 + n * 64 + seg * 8) = gv[j];
    }
}

// W1p frags for one 64-k tile (2 chunks x 2 perm-halves); lanes lq<2 real.
__device__ __forceinline__ void load_wf(const bf16_t* __restrict__ W1p, int k0,
                                        int l15, int lq, bf16x8 wf[4]) {
#pragma unroll
    for (int i = 0; i < 4; ++i) wf[i] = zero8();
    if (lq < 2) {
        const int base = (k0 >> 5) * 2;
#pragma unroll
        for (int i = 0; i < 4; ++i)
            wf[i] = *(const bf16x8*)(W1p + (size_t)((base + i) * 16 + l15) * 16 + lq * 8);
    }
}

// one 64-k tile: B frags from LDS, h in registers (layout-matched MFMA), mains.
// wave tile 32m x 64n (wn fixed = 0 for the whole block).
__device__ __forceinline__ void compute_tile(const bf16_t* Bb, const bf16x8 wf[4],
                                             const bf16x8 zfrag[2],
                                             int l15, int lq,
                                             f32x4 acc[2][4]) {
    bf16x8 bfr[2][4];
#pragma unroll
    for (int c = 0; c < 2; ++c)
#pragma unroll
        for (int nt = 0; nt < 4; ++nt) {
            int r = nt * 16 + l15;
            int s = (c * 4 + lq) ^ (r & 7);
            bfr[c][nt] = *(const bf16x8*)(Bb + r * 64 + s * 8);
        }

    bf16x8 af[2][2];
#pragma unroll
    for (int mt = 0; mt < 2; ++mt)
#pragma unroll
        for (int c = 0; c < 2; ++c) {
            f32x4 h0 = (f32x4){0.f, 0.f, 0.f, 0.f};
            f32x4 h1 = (f32x4){0.f, 0.f, 0.f, 0.f};
            h0 = __builtin_amdgcn_mfma_f32_16x16x32_bf16(wf[c * 2 + 0], zfrag[mt], h0, 0, 0, 0);
            h1 = __builtin_amdgcn_mfma_f32_16x16x32_bf16(wf[c * 2 + 1], zfrag[mt], h1, 0, 0, 0);
            bf16x8 a;
#pragma unroll
            for (int r = 0; r < 4; ++r) {
                a[r]     = (bf16_t)fmaxf(h0[r], 0.f);
                a[r + 4] = (bf16_t)fmaxf(h1[r], 0.f);
            }
            af[mt][c] = a;
        }

#pragma unroll
    for (int c = 0; c < 2; ++c)
#pragma unroll
        for (int mt = 0; mt < 2; ++mt)
#pragma unroll
            for (int nt = 0; nt < 4; ++nt)
                acc[mt][nt] = __builtin_amdgcn_mfma_f32_16x16x32_bf16(
                    af[mt][c], bfr[c][nt], acc[mt][nt], 0, 0, 0);
}

// ---------------------------------------------------------------------------
// Fused GEMM: out = relu(z@W1+b1) @ W2 + b2
// Block 128m x 64n, 256 thr = 4 waves (4m x 1n), wave 32m x 64n.
// Grid 512 = 2 blocks/CU -> cross-block overlap hides barrier drains.
// BK=128 segments, double-buffered (2 x 16KB LDS), ONE barrier per segment
// (write buf[1-cur] after compute; next top-of-loop barrier publishes it).
// h entirely in registers via layout-matched h-MFMA (permuted W1p).
// ---------------------------------------------------------------------------
__global__ __launch_bounds__(256, 2)
void ffq_gemm_kernel(const bf16_t* __restrict__ zb,    // [8192][16]
                     const bf16_t* __restrict__ W1p,   // [2048][16] permuted
                     const bf16_t* __restrict__ W2t,   // [512][2048]
                     const float* __restrict__ b2,
                     float* __restrict__ out)          // [8192][512]
{
    __shared__ bf16_t Blds[2][2 * 64 * 64];   // 2 bufs x (two 64x64 k-tiles)

    const int t = threadIdx.x;
    const int w = t >> 6, l = t & 63;
    const int m_base = blockIdx.y * 128;
    const int n_base = blockIdx.x * 64;
    const int wm = w;                          // 4 m-slots of 32
    const int l15 = l & 15, lq = l >> 4;

    // persistent z^T B-frags for this wave's two 16-row m-tiles
    bf16x8 zfrag[2];
#pragma unroll
    for (int mt = 0; mt < 2; ++mt) {
        zfrag[mt] = zero8();
        if (lq < 2)
            zfrag[mt] = *(const bf16x8*)(zb + (size_t)(m_base + wm * 32 + mt * 16 + l15) * 16 + lq * 8);
    }

    f32x4 acc[2][4];
#pragma unroll
    for (int mt = 0; mt < 2; ++mt)
#pragma unroll
        for (int nt = 0; nt < 4; ++nt)
            acc[mt][nt] = (f32x4){0.f, 0.f, 0.f, 0.f};

    uint4 gv[4];

    // prologue: segment 0 -> buf0
    load_B(W2t, n_base, 0, t, gv);
    write_B(Blds[0], t, gv);

    for (int s = 0; s < NSEG; ++s) {
        const int cur = s & 1;
        __syncthreads();                               // publish buf[cur]
        if (s + 1 < NSEG) load_B(W2t, n_base, (s + 1) * 128, t, gv);

#pragma unroll
        for (int tt = 0; tt < 2; ++tt) {
            bf16x8 wf[4];
            load_wf(W1p, s * 128 + tt * 64, l15, lq, wf);
            compute_tile(Blds[cur] + tt * 4096, wf, zfrag, l15, lq, acc);
        }

        if (s + 1 < NSEG) write_B(Blds[1 - cur], t, gv);   // precise vmcnt
    }

    // ---- epilogue: C/D layout col=lane&15, row=(lane>>4)*4+r ----
#pragma unroll
    for (int nt = 0; nt < 4; ++nt) {
        int col = n_base + nt * 16 + l15;
        float bias = b2[col];
#pragma unroll
        for (int mt = 0; mt < 2; ++mt) {
#pragma unroll
            for (int r = 0; r < 4; ++r) {
                int row = m_base + wm * 32 + mt * 16 + lq * 4 + r;
                out[(size_t)row * N_TOT + col] = acc[mt][nt][r] + bias;
            }
        }
    }
}

extern "C" void kernel_launch(void* const* d_in, const int* in_sizes, int n_in,
                              void* d_out, int out_size, void* d_ws, size_t ws_size,
                              hipStream_t stream) {
    const float* x     = (const float*)d_in[0];
    const float* theta = (const float*)d_in[1];
    const float* W1    = (const float*)d_in[2];
    const float* b1    = (const float*)d_in[3];
    const float* W2    = (const float*)d_in[4];
    const float* b2    = (const float*)d_in[5];
    float* out = (float*)d_out;

    // ws: [0,2MB) W2t ; [2MB,2.25MB) zb[8192][16] ; then W1p[2048][16]
    const size_t W2T_BYTES = (size_t)N_TOT * K_TOT * sizeof(bf16_t);  // 2 MB
    const size_t ZB_BYTES  = (size_t)M_TOT * 16 * sizeof(bf16_t);     // 256 KB

    bf16_t* W2t = (bf16_t*)d_ws;
    bf16_t* zb  = (bf16_t*)((char*)d_ws + W2T_BYTES);
    bf16_t* W1p = (bf16_t*)((char*)d_ws + W2T_BYTES + ZB_BYTES);

    prep4_kernel<<<296, 256, 0, stream>>>(x, theta, W1, b1, W2, W2t, zb, W1p);

    dim3 grid(N_TOT / 64, M_TOT / 128);   // (8, 64) = 512 blocks, 2/CU
    ffq_gemm_kernel<<<grid, 256, 0, stream>>>(zb, W1p, W2t, b2, out);
}